// Round 2
// baseline (2615.766 us; speedup 1.0000x reference)
//
#include <hip/hip_runtime.h>
#include <hip/hip_bf16.h>

#define BB 8
#define NN 4096
#define DIN 128
#define DOUT 256
#define SS 1024
#define KK 16

// Workspace in device globals: immune to ws_size, graph-capture-safe.
// Everything is zeroed / fully rewritten on every call.
__device__ float g_g[(size_t)BB * NN * DOUT];     // 32 MB: g = feat @ W^T + b
__device__ int   g_knn[BB * SS * KK];
__device__ int   g_wcount[BB * NN];
__device__ float g_S1[DOUT];
__device__ float g_S2[DOUT];

// ---------------------------------------------------------------------------
// Kernel 1: blocks [0,8)   : FPS per batch (f64 distances, exact argmax+tie)
//           blocks [8,2056): GEMM g = feat @ W^T + b  (M=32768,K=128,N=256)
//           blocks [2056,2088): zero wcount / S1 / S2
// ---------------------------------------------------------------------------
__global__ __launch_bounds__(512) void k_fused1(
    const float* __restrict__ feat, const float* __restrict__ xyz,
    const float* __restrict__ W, const float* __restrict__ bias,
    float* __restrict__ out)
{
    __shared__ __align__(16) float smem[16384]; // xyz as float4[4096] OR gemm tiles
    __shared__ double swd[8];
    __shared__ int    swi[8];
    __shared__ int    sh_widx;

    if (blockIdx.x < BB) {
        const int b = blockIdx.x, tid = threadIdx.x;
        const float* bx = xyz + (size_t)b * NN * 3;
        for (int i = 0; i < 8; ++i) {
            int p = tid + i * 512;
            smem[p*4]   = bx[p*3];
            smem[p*4+1] = bx[p*3+1];
            smem[p*4+2] = bx[p*3+2];
            smem[p*4+3] = 0.f;
        }
        __syncthreads();
        float px[8], py[8], pz[8];
        double dist[8];
        const int gbase = tid * 8;
        #pragma unroll
        for (int r = 0; r < 8; ++r) {
            float4 v = *(float4*)&smem[(gbase + r) * 4];
            px[r] = v.x; py[r] = v.y; pz[r] = v.z; dist[r] = 1e10;
        }
        double lx = (double)smem[0], ly = (double)smem[1], lz = (double)smem[2];
        float* oxyz = out + (size_t)BB * SS * DOUT;
        if (tid == 0) {
            oxyz[(size_t)(b*SS)*3]   = smem[0];
            oxyz[(size_t)(b*SS)*3+1] = smem[1];
            oxyz[(size_t)(b*SS)*3+2] = smem[2];
        }
        for (int s = 1; s < SS; ++s) {
            double bestd = -1.0; int besti = 0;
            #pragma unroll
            for (int r = 0; r < 8; ++r) {
                double dx = (double)px[r] - lx;
                double dy = (double)py[r] - ly;
                double dz = (double)pz[r] - lz;
                double d = dx*dx + dy*dy + dz*dz;
                double nd = dist[r] < d ? dist[r] : d;
                dist[r] = nd;
                if (nd > bestd) { bestd = nd; besti = gbase + r; }
            }
            #pragma unroll
            for (int m = 1; m < 64; m <<= 1) {
                double od = __shfl_xor(bestd, m);
                int    oi = __shfl_xor(besti, m);
                if (od > bestd || (od == bestd && oi < besti)) { bestd = od; besti = oi; }
            }
            if ((tid & 63) == 0) { swd[tid >> 6] = bestd; swi[tid >> 6] = besti; }
            __syncthreads();
            if (tid < 64) {
                double d2v = (tid < 8) ? swd[tid] : -1.0;
                int    i2  = (tid < 8) ? swi[tid] : 0;
                #pragma unroll
                for (int m = 1; m < 8; m <<= 1) {
                    double od = __shfl_xor(d2v, m);
                    int    oi = __shfl_xor(i2, m);
                    if (od > d2v || (od == d2v && oi < i2)) { d2v = od; i2 = oi; }
                }
                if (tid == 0) {
                    sh_widx = i2;
                    oxyz[(size_t)(b*SS+s)*3]   = smem[i2*4];
                    oxyz[(size_t)(b*SS+s)*3+1] = smem[i2*4+1];
                    oxyz[(size_t)(b*SS+s)*3+2] = smem[i2*4+2];
                }
            }
            __syncthreads();
            int widx = sh_widx;
            lx = (double)smem[widx*4];
            ly = (double)smem[widx*4+1];
            lz = (double)smem[widx*4+2];
        }
    } else if (blockIdx.x < BB + 2048) {
        // GEMM: BM=64, BN=64, BK=32, 512 threads, 2x4 per thread
        int gi = blockIdx.x - BB;
        int mt = gi & 511, nt = gi >> 9;
        int rbase = mt * 64, cbase = nt * 64;
        float* As = smem;            // [64][36]
        float* Bs = smem + 64 * 36;  // [32][68]
        int tid = threadIdx.x;
        int tx = tid & 15, ty = tid >> 4;
        int c0 = tx * 4, r0 = ty * 2;
        int lr = tid >> 3;          // 0..63
        int lk = (tid & 7) * 4;     // 0..28
        float acc[2][4] = {{0.f,0.f,0.f,0.f},{0.f,0.f,0.f,0.f}};
        for (int kc = 0; kc < 4; ++kc) {
            __syncthreads();
            float4 av = *(const float4*)&feat[(size_t)(rbase + lr) * DIN + kc*32 + lk];
            *(float4*)&As[lr * 36 + lk] = av;
            float4 wv = *(const float4*)&W[(size_t)(cbase + lr) * DIN + kc*32 + lk];
            Bs[(lk+0)*68 + lr] = wv.x;
            Bs[(lk+1)*68 + lr] = wv.y;
            Bs[(lk+2)*68 + lr] = wv.z;
            Bs[(lk+3)*68 + lr] = wv.w;
            __syncthreads();
            const float* Ar0 = &As[r0 * 36];
            const float* Ar1 = Ar0 + 36;
            #pragma unroll
            for (int k = 0; k < 32; ++k) {
                float a0 = Ar0[k], a1 = Ar1[k];
                float4 bv = *(float4*)&Bs[k * 68 + c0];
                acc[0][0] += a0 * bv.x; acc[0][1] += a0 * bv.y;
                acc[0][2] += a0 * bv.z; acc[0][3] += a0 * bv.w;
                acc[1][0] += a1 * bv.x; acc[1][1] += a1 * bv.y;
                acc[1][2] += a1 * bv.z; acc[1][3] += a1 * bv.w;
            }
        }
        float4 bb4 = *(const float4*)&bias[cbase + c0];
        float4 o0, o1;
        o0.x = acc[0][0] + bb4.x; o0.y = acc[0][1] + bb4.y;
        o0.z = acc[0][2] + bb4.z; o0.w = acc[0][3] + bb4.w;
        o1.x = acc[1][0] + bb4.x; o1.y = acc[1][1] + bb4.y;
        o1.z = acc[1][2] + bb4.z; o1.w = acc[1][3] + bb4.w;
        *(float4*)&g_g[(size_t)(rbase + r0)     * DOUT + cbase + c0] = o0;
        *(float4*)&g_g[(size_t)(rbase + r0 + 1) * DOUT + cbase + c0] = o1;
    } else {
        int zi = blockIdx.x - (BB + 2048);
        int t = zi * 512 + threadIdx.x;     // 0..16383
        g_wcount[t] = 0;
        g_wcount[t + 16384] = 0;
        if (t < DOUT) { g_S1[t] = 0.f; g_S2[t] = 0.f; }
    }
}

// ---------------------------------------------------------------------------
// Kernel 2: KNN (f64 distances, exact top-16 set with index tie-break)
//           one query per wave, 4 waves/block, 2048 blocks
// ---------------------------------------------------------------------------
__global__ __launch_bounds__(256) void k_knn(
    const float* __restrict__ xyz, const float* __restrict__ out)
{
    __shared__ __align__(16) float4 xp[NN];             // 64 KB
    __shared__ double topd[256][KK];                    // 32 KB
    __shared__ unsigned short topi[256][KK];            //  8 KB
    const int tid = threadIdx.x;
    const int lane = tid & 63;
    const int q = blockIdx.x * 4 + (tid >> 6);          // 0..8191, block stays in one batch
    const int b = q >> 10;
    const float* bx = xyz + (size_t)b * NN * 3;
    for (int i = 0; i < 16; ++i) {
        int p = tid + i * 256;
        float4 v; v.x = bx[p*3]; v.y = bx[p*3+1]; v.z = bx[p*3+2]; v.w = 0.f;
        xp[p] = v;
    }
    double* td = topd[tid];
    unsigned short* ti = topi[tid];
    #pragma unroll
    for (int i = 0; i < KK; ++i) td[i] = 1e30;
    __syncthreads();

    const float* sx = out + (size_t)BB * SS * DOUT + (size_t)q * 3;
    const double qx = (double)sx[0], qy = (double)sx[1], qz = (double)sx[2];
    double kmax = 1e30;
    for (int t = 0; t < 64; ++t) {
        int n = t * 64 + lane;                           // monotone per lane
        float4 p = xp[n];
        double dx = qx - (double)p.x;
        double dy = qy - (double)p.y;
        double dz = qz - (double)p.z;
        double d2 = dx*dx + dy*dy + dz*dz;
        if (d2 < kmax) {
            int pos = KK - 1;
            while (pos > 0 && td[pos-1] > d2) {
                td[pos] = td[pos-1]; ti[pos] = ti[pos-1]; --pos;
            }
            td[pos] = d2; ti[pos] = (unsigned short)n;
            kmax = td[KK-1];
        }
    }
    // merge 64 sorted lists -> global smallest 16 (ties: smallest index)
    int ptr = 0;
    for (int r = 0; r < KK; ++r) {
        double md; int mi;
        if (ptr < KK) { md = td[ptr]; mi = (int)ti[ptr]; }
        else          { md = 1e300;  mi = 0x7FFFFFFF; }
        double wd = md; int wi = mi;
        #pragma unroll
        for (int m = 1; m < 64; m <<= 1) {
            double od = __shfl_xor(wd, m);
            int    oi = __shfl_xor(wi, m);
            if (od < wd || (od == wd && oi < wi)) { wd = od; wi = oi; }
        }
        if (wd == md && wi == mi) ++ptr;
        if (lane == 0) {
            g_knn[(size_t)q * KK + r] = wi;
            atomicAdd(&g_wcount[b * NN + wi], 1);
        }
    }
}

// ---------------------------------------------------------------------------
// Kernel 3: weighted per-channel sums for BN stats
// ---------------------------------------------------------------------------
__global__ __launch_bounds__(256) void k_stats()
{
    int tid = threadIdx.x;
    int rbase = blockIdx.x * 512;
    float a1 = 0.f, a2 = 0.f;
    for (int i = 0; i < 512; ++i) {
        int row = rbase + i;
        int w = g_wcount[row];
        if (w) {
            float v = g_g[(size_t)row * DOUT + tid];
            float wf = (float)w;
            a1 += wf * v;
            a2 += wf * v * v;
        }
    }
    atomicAdd(&g_S1[tid], a1);
    atomicAdd(&g_S2[tid], a2);
}

// ---------------------------------------------------------------------------
// Kernel 4: per-query max over K, then BN affine + ReLU (commutes: scale>0)
// ---------------------------------------------------------------------------
__global__ __launch_bounds__(256) void k_final(
    const float* __restrict__ gamma, const float* __restrict__ beta,
    float* __restrict__ out)
{
    int w = threadIdx.x >> 6, lane = threadIdx.x & 63;
    int q = blockIdx.x * 4 + w;       // 0..8191
    int b = q >> 10;
    int c = lane * 4;
    const int* ki = g_knn + (size_t)q * KK;
    float4 m; m.x = m.y = m.z = m.w = -1e30f;
    for (int k = 0; k < KK; ++k) {
        int idx = ki[k];
        float4 v = *(const float4*)&g_g[((size_t)(b * NN + idx)) * DOUT + c];
        m.x = fmaxf(m.x, v.x); m.y = fmaxf(m.y, v.y);
        m.z = fmaxf(m.z, v.z); m.w = fmaxf(m.w, v.w);
    }
    const float inv = 1.0f / 131072.0f;
    float4 s1 = *(const float4*)&g_S1[c];
    float4 s2 = *(const float4*)&g_S2[c];
    float4 ga = *(const float4*)&gamma[c];
    float4 be = *(const float4*)&beta[c];
    float4 o;
    {
        float mean = s1.x * inv; float var = s2.x * inv - mean * mean;
        float rs = rsqrtf(var + 1e-5f);
        float t = ga.x * (m.x - mean); t = t * rs; t += be.x; o.x = fmaxf(t, 0.f);
    }
    {
        float mean = s1.y * inv; float var = s2.y * inv - mean * mean;
        float rs = rsqrtf(var + 1e-5f);
        float t = ga.y * (m.y - mean); t = t * rs; t += be.y; o.y = fmaxf(t, 0.f);
    }
    {
        float mean = s1.z * inv; float var = s2.z * inv - mean * mean;
        float rs = rsqrtf(var + 1e-5f);
        float t = ga.z * (m.z - mean); t = t * rs; t += be.z; o.z = fmaxf(t, 0.f);
    }
    {
        float mean = s1.w * inv; float var = s2.w * inv - mean * mean;
        float rs = rsqrtf(var + 1e-5f);
        float t = ga.w * (m.w - mean); t = t * rs; t += be.w; o.w = fmaxf(t, 0.f);
    }
    *(float4*)&out[(size_t)q * DOUT + c] = o;
}

extern "C" void kernel_launch(void* const* d_in, const int* in_sizes, int n_in,
                              void* d_out, int out_size, void* d_ws, size_t ws_size,
                              hipStream_t stream) {
    (void)in_sizes; (void)n_in; (void)out_size; (void)d_ws; (void)ws_size;
    const float* feat  = (const float*)d_in[0];
    const float* xyz   = (const float*)d_in[1];
    const float* W     = (const float*)d_in[2];
    const float* bias  = (const float*)d_in[3];
    const float* gamma = (const float*)d_in[4];
    const float* beta  = (const float*)d_in[5];
    float* out = (float*)d_out;

    k_fused1<<<BB + 2048 + 32, 512, 0, stream>>>(feat, xyz, W, bias, out);
    k_knn   <<<BB * SS / 4, 256, 0, stream>>>(xyz, out);
    k_stats <<<64, 256, 0, stream>>>();
    k_final <<<2048, 256, 0, stream>>>(gamma, beta, out);
}

// Round 4
// 1503.740 us; speedup vs baseline: 1.7395x; 1.7395x over previous
//
#include <hip/hip_runtime.h>
#include <hip/hip_bf16.h>

#define BB 8
#define NN 4096
#define DIN 128
#define DOUT 256
#define SS 1024
#define KK 16

// Workspace in device globals: immune to ws_size, graph-capture-safe.
// Everything is zeroed / fully rewritten on every call.
__device__ float g_g[(size_t)BB * NN * DOUT];     // 32 MB: g = feat @ W^T + b
__device__ int   g_knn[BB * SS * KK];
__device__ int   g_wcount[BB * NN];
__device__ float g_S1[DOUT];
__device__ float g_S2[DOUT];

// ---------------------------------------------------------------------------
// Kernel 1: blocks [0,8)   : FPS per batch (exact f64 argmax, f32 prefilter)
//           blocks [8,2056): GEMM g = feat @ W^T + b  (M=32768,K=128,N=256)
//           blocks [2056,2088): zero wcount / S1 / S2
// ---------------------------------------------------------------------------
__global__ __launch_bounds__(512) void k_fused1(
    const float* __restrict__ feat, const float* __restrict__ xyz,
    const float* __restrict__ W, const float* __restrict__ bias,
    float* __restrict__ out)
{
    __shared__ __align__(16) float smem[16384]; // xyz as float4[4096] OR gemm tiles
    __shared__ unsigned swk[8];
    __shared__ unsigned long long lds_hi[2];    // double-buffered resolve slots
    __shared__ unsigned lds_idx[2];

    if (blockIdx.x < BB) {
        #pragma clang fp contract(off)
        // FPS. Distance values are bit-identical to numpy float64:
        // dx=x-lx (f64 sub), m=dx*dx (f64 mul, NOT fused), d=(m1+m2)+m3.
        const int b = blockIdx.x, tid = threadIdx.x;
        const float* bx = xyz + (size_t)b * NN * 3;
        for (int i = 0; i < 8; ++i) {
            int p = tid + i * 512;
            float4 v; v.x = bx[p*3]; v.y = bx[p*3+1]; v.z = bx[p*3+2]; v.w = 0.f;
            ((float4*)smem)[p] = v;
        }
        if (tid == 0) {
            lds_hi[0] = 0ull; lds_hi[1] = 0ull;
            lds_idx[0] = 0xFFFFFFFFu; lds_idx[1] = 0xFFFFFFFFu;
        }
        __syncthreads();
        double cx[8], cy[8], cz[8], dist[8];
        unsigned fb[8];
        const int gbase = tid * 8;
        #pragma unroll
        for (int r = 0; r < 8; ++r) {
            float4 v = ((float4*)smem)[gbase + r];
            cx[r] = (double)v.x; cy[r] = (double)v.y; cz[r] = (double)v.z;
            dist[r] = 1e10;   // f32(1e10) == 1e10 exactly
        }
        double lx = (double)smem[0], ly = (double)smem[1], lz = (double)smem[2];
        float* oxyz = out + (size_t)BB * SS * DOUT;
        if (tid == 0) {
            oxyz[(size_t)(b*SS)*3]   = smem[0];
            oxyz[(size_t)(b*SS)*3+1] = smem[1];
            oxyz[(size_t)(b*SS)*3+2] = smem[2];
        }
        for (int s = 1; s < SS; ++s) {
            const int sl = s & 1;
            unsigned mf = 0u;
            #pragma unroll
            for (int r = 0; r < 8; ++r) {
                double dx = cx[r] - lx;
                double dy = cy[r] - ly;
                double dz = cz[r] - lz;
                double m1 = dx*dx, m2 = dy*dy, m3 = dz*dz;
                double d = (m1 + m2) + m3;
                double nd = dist[r] < d ? dist[r] : d;
                dist[r] = nd;
                unsigned u = __float_as_uint((float)nd);  // monotone for nonneg
                fb[r] = u;
                mf = u > mf ? u : mf;
            }
            // wave max of f32 prefilter key
            #pragma unroll
            for (int m = 1; m < 64; m <<= 1) {
                unsigned o = __shfl_xor(mf, m);
                mf = o > mf ? o : mf;
            }
            if ((tid & 63) == 0) swk[tid >> 6] = mf;
            __syncthreads();                               // B1
            unsigned M = swk[0];
            #pragma unroll
            for (int i = 1; i < 8; ++i) { unsigned o = swk[i]; M = o > M ? o : M; }
            if (tid == 0) {                                // reset NEXT slot (safe: next
                lds_hi[sl ^ 1] = 0ull;                     // slot untouched until next B1)
                lds_idx[sl ^ 1] = 0xFFFFFFFFu;
            }
            // exact stage 1: max f64 bits among f32-tied candidates
            #pragma unroll
            for (int r = 0; r < 8; ++r)
                if (fb[r] == M)
                    atomicMax(&lds_hi[sl], (unsigned long long)__double_as_longlong(dist[r]));
            __syncthreads();                               // B2
            unsigned long long hi = lds_hi[sl];
            // exact stage 2: min index among exact f64 ties (np argmax = first occurrence)
            #pragma unroll
            for (int r = 0; r < 8; ++r)
                if ((unsigned long long)__double_as_longlong(dist[r]) == hi)
                    atomicMin(&lds_idx[sl], (unsigned)(gbase + r));
            __syncthreads();                               // B3
            int widx = (int)lds_idx[sl];
            float4 c = ((float4*)smem)[widx];
            lx = (double)c.x; ly = (double)c.y; lz = (double)c.z;
            if (tid == 0) {
                oxyz[(size_t)(b*SS+s)*3]   = c.x;
                oxyz[(size_t)(b*SS+s)*3+1] = c.y;
                oxyz[(size_t)(b*SS+s)*3+2] = c.z;
            }
        }
    } else if (blockIdx.x < BB + 2048) {
        // GEMM: BM=64, BN=64, BK=32, 512 threads, 2x4 per thread (validated r2)
        int gi = blockIdx.x - BB;
        int mt = gi & 511, nt = gi >> 9;
        int rbase = mt * 64, cbase = nt * 64;
        float* As = smem;            // [64][36]
        float* Bs = smem + 64 * 36;  // [32][68]
        int tid = threadIdx.x;
        int tx = tid & 15, ty = tid >> 4;
        int c0 = tx * 4, r0 = ty * 2;
        int lr = tid >> 3;          // 0..63
        int lk = (tid & 7) * 4;     // 0..28
        float acc[2][4] = {{0.f,0.f,0.f,0.f},{0.f,0.f,0.f,0.f}};
        for (int kc = 0; kc < 4; ++kc) {
            __syncthreads();
            float4 av = *(const float4*)&feat[(size_t)(rbase + lr) * DIN + kc*32 + lk];
            *(float4*)&As[lr * 36 + lk] = av;
            float4 wv = *(const float4*)&W[(size_t)(cbase + lr) * DIN + kc*32 + lk];
            Bs[(lk+0)*68 + lr] = wv.x;
            Bs[(lk+1)*68 + lr] = wv.y;
            Bs[(lk+2)*68 + lr] = wv.z;
            Bs[(lk+3)*68 + lr] = wv.w;
            __syncthreads();
            const float* Ar0 = &As[r0 * 36];
            const float* Ar1 = Ar0 + 36;
            #pragma unroll
            for (int k = 0; k < 32; ++k) {
                float a0 = Ar0[k], a1 = Ar1[k];
                float4 bv = *(float4*)&Bs[k * 68 + c0];
                acc[0][0] += a0 * bv.x; acc[0][1] += a0 * bv.y;
                acc[0][2] += a0 * bv.z; acc[0][3] += a0 * bv.w;
                acc[1][0] += a1 * bv.x; acc[1][1] += a1 * bv.y;
                acc[1][2] += a1 * bv.z; acc[1][3] += a1 * bv.w;
            }
        }
        float4 bb4 = *(const float4*)&bias[cbase + c0];
        float4 o0, o1;
        o0.x = acc[0][0] + bb4.x; o0.y = acc[0][1] + bb4.y;
        o0.z = acc[0][2] + bb4.z; o0.w = acc[0][3] + bb4.w;
        o1.x = acc[1][0] + bb4.x; o1.y = acc[1][1] + bb4.y;
        o1.z = acc[1][2] + bb4.z; o1.w = acc[1][3] + bb4.w;
        *(float4*)&g_g[(size_t)(rbase + r0)     * DOUT + cbase + c0] = o0;
        *(float4*)&g_g[(size_t)(rbase + r0 + 1) * DOUT + cbase + c0] = o1;
    } else {
        int zi = blockIdx.x - (BB + 2048);
        int t = zi * 512 + threadIdx.x;     // 0..16383
        g_wcount[t] = 0;
        g_wcount[t + 16384] = 0;
        if (t < DOUT) { g_S1[t] = 0.f; g_S2[t] = 0.f; }
    }
}

// ---------------------------------------------------------------------------
// Kernel 2: KNN via per-wave histogram select + exact f64 resolve.
//   16 queries/block (1024 thr, 16 waves), 512 blocks, ~104 KB LDS.
//   f32 prefilter (deterministic fmaf form, identical in both passes) buckets
//   distances by float bits (512 bins, ~6% rel width >> 1e-7 f32 error), so
//   candidates (buckets <= Tb+1) provably contain the exact f64 top-16.
// ---------------------------------------------------------------------------
__global__ __launch_bounds__(1024) void k_knn(
    const float* __restrict__ xyz, const float* __restrict__ out)
{
    __shared__ __align__(16) float4 pts[NN];   // 64 KB
    __shared__ unsigned hist[16][512];         // 32 KB
    __shared__ int cand[16][128];              //  8 KB
    __shared__ int cnt[16];
    const int tid = threadIdx.x, lane = tid & 63, w = tid >> 6;
    const int q = blockIdx.x * 16 + w;         // 64 blocks per batch
    const int b = blockIdx.x >> 6;
    const float* bx = xyz + (size_t)b * NN * 3;
    for (int i = 0; i < 4; ++i) {
        int p = tid + i * 1024;
        float4 v; v.x = bx[p*3]; v.y = bx[p*3+1]; v.z = bx[p*3+2]; v.w = 0.f;
        pts[p] = v;
    }
    { unsigned* h = &hist[0][0];
      #pragma unroll
      for (int i = 0; i < 8; ++i) h[tid + i * 1024] = 0u; }
    if (tid < 16) cnt[tid] = 0;
    __syncthreads();

    const float* sx = out + (size_t)BB * SS * DOUT + (size_t)q * 3;
    const float qxf = sx[0], qyf = sx[1], qzf = sx[2];
    // pass 1: histogram f32 distance bits
    unsigned minub = 0xFFFFFFFFu;
    for (int t = 0; t < 64; ++t) {
        int n = t * 64 + lane;
        float4 p = pts[n];
        float dx = qxf - p.x, dy = qyf - p.y, dz = qzf - p.z;
        float df = fmaf(dz, dz, fmaf(dy, dy, dx * dx));
        unsigned ub = __float_as_uint(df);
        minub = ub < minub ? ub : minub;
        unsigned bk = ub < 0x30800000u ? 0u : ((ub - 0x30800000u) >> 19);
        bk = bk > 511u ? 511u : bk;
        atomicAdd(&hist[w][bk], 1u);
    }
    #pragma unroll
    for (int m = 1; m < 64; m <<= 1) {
        unsigned o = __shfl_xor(minub, m);
        minub = o < minub ? o : minub;
    }
    unsigned mb = minub < 0x30800000u ? 0u : ((minub - 0x30800000u) >> 19);
    mb = mb > 511u ? 511u : mb;
    // scan own histogram row for the bucket containing rank 16
    int Tb = 511;
    unsigned base = 0;
    for (int ch = (int)(mb >> 6); ch < 8; ++ch) {
        unsigned v = hist[w][ch * 64 + lane];
        #pragma unroll
        for (int m = 1; m < 64; m <<= 1) {
            unsigned t2 = __shfl_up(v, m);
            if (lane >= m) v += t2;
        }
        unsigned tot = __shfl(v, 63);
        unsigned long long msk = __ballot(base + v >= 16u);
        if (msk) { Tb = ch * 64 + (__ffsll(msk) - 1); break; }
        base += tot;
    }
    unsigned Tcap = (unsigned)Tb + 1u; Tcap = Tcap > 511u ? 511u : Tcap;
    // pass 2: collect candidates (identical df computation => identical bits)
    for (int t = 0; t < 64; ++t) {
        int n = t * 64 + lane;
        float4 p = pts[n];
        float dx = qxf - p.x, dy = qyf - p.y, dz = qzf - p.z;
        float df = fmaf(dz, dz, fmaf(dy, dy, dx * dx));
        unsigned ub = __float_as_uint(df);
        unsigned bk = ub < 0x30800000u ? 0u : ((ub - 0x30800000u) >> 19);
        bk = bk > 511u ? 511u : bk;
        if (bk <= Tcap) {
            int slot = atomicAdd(&cnt[w], 1);
            if (slot < 128) cand[w][slot] = n;
        }
    }
    {
        #pragma clang fp contract(off)
        // wave-local LDS produced by own lanes: no block barrier needed
        int count = cnt[w]; count = count > 128 ? 128 : count;
        const double qx = (double)qxf, qy = (double)qyf, qz = (double)qzf;
        int i0 = lane < count ? cand[w][lane] : -1;
        int i1 = (lane + 64) < count ? cand[w][lane + 64] : -1;
        double d0 = 1e300, d1 = 1e300;
        if (i0 >= 0) {
            float4 p = pts[i0];
            double dx = qx - (double)p.x, dy = qy - (double)p.y, dz = qz - (double)p.z;
            double m1 = dx*dx, m2 = dy*dy, m3 = dz*dz;
            d0 = (m1 + m2) + m3;
        }
        if (i1 >= 0) {
            float4 p = pts[i1];
            double dx = qx - (double)p.x, dy = qy - (double)p.y, dz = qz - (double)p.z;
            double m1 = dx*dx, m2 = dy*dy, m3 = dz*dz;
            d1 = (m1 + m2) + m3;
        }
        int r0 = 0, r1 = 0;
        for (int i = 0; i < count; ++i) {
            double od; int oi;
            if (i < 64) { od = __shfl(d0, i);      oi = __shfl(i0, i); }
            else        { od = __shfl(d1, i - 64); oi = __shfl(i1, i - 64); }
            if ((od < d0) || (od == d0 && oi < i0)) ++r0;
            if ((od < d1) || (od == d1 && oi < i1)) ++r1;
        }
        if (i0 >= 0 && r0 < KK) {
            g_knn[(size_t)q * KK + r0] = i0;
            atomicAdd(&g_wcount[b * NN + i0], 1);
        }
        if (i1 >= 0 && r1 < KK) {
            g_knn[(size_t)q * KK + r1] = i1;
            atomicAdd(&g_wcount[b * NN + i1], 1);
        }
    }
}

// ---------------------------------------------------------------------------
// Kernel 3: weighted per-channel sums for BN stats
// ---------------------------------------------------------------------------
__global__ __launch_bounds__(256) void k_stats()
{
    int tid = threadIdx.x;
    int rbase = blockIdx.x * 128;
    float a1 = 0.f, a2 = 0.f;
    for (int i = 0; i < 128; ++i) {
        int row = rbase + i;
        int w = g_wcount[row];
        if (w) {
            float v = g_g[(size_t)row * DOUT + tid];
            float wf = (float)w;
            a1 += wf * v;
            a2 += wf * v * v;
        }
    }
    atomicAdd(&g_S1[tid], a1);
    atomicAdd(&g_S2[tid], a2);
}

// ---------------------------------------------------------------------------
// Kernel 4: per-query max over K, then BN affine + ReLU (commutes: scale>0)
// ---------------------------------------------------------------------------
__global__ __launch_bounds__(256) void k_final(
    const float* __restrict__ gamma, const float* __restrict__ beta,
    float* __restrict__ out)
{
    int w = threadIdx.x >> 6, lane = threadIdx.x & 63;
    int q = blockIdx.x * 4 + w;       // 0..8191
    int b = q >> 10;
    int c = lane * 4;
    const int* ki = g_knn + (size_t)q * KK;
    float4 m; m.x = m.y = m.z = m.w = -1e30f;
    for (int k = 0; k < KK; ++k) {
        int idx = ki[k];
        float4 v = *(const float4*)&g_g[((size_t)(b * NN + idx)) * DOUT + c];
        m.x = fmaxf(m.x, v.x); m.y = fmaxf(m.y, v.y);
        m.z = fmaxf(m.z, v.z); m.w = fmaxf(m.w, v.w);
    }
    const float inv = 1.0f / 131072.0f;
    float4 s1 = *(const float4*)&g_S1[c];
    float4 s2 = *(const float4*)&g_S2[c];
    float4 ga = *(const float4*)&gamma[c];
    float4 be = *(const float4*)&beta[c];
    float4 o;
    {
        float mean = s1.x * inv; float var = s2.x * inv - mean * mean;
        float rs = rsqrtf(var + 1e-5f);
        float t = ga.x * (m.x - mean); t = t * rs; t += be.x; o.x = fmaxf(t, 0.f);
    }
    {
        float mean = s1.y * inv; float var = s2.y * inv - mean * mean;
        float rs = rsqrtf(var + 1e-5f);
        float t = ga.y * (m.y - mean); t = t * rs; t += be.y; o.y = fmaxf(t, 0.f);
    }
    {
        float mean = s1.z * inv; float var = s2.z * inv - mean * mean;
        float rs = rsqrtf(var + 1e-5f);
        float t = ga.z * (m.z - mean); t = t * rs; t += be.z; o.z = fmaxf(t, 0.f);
    }
    {
        float mean = s1.w * inv; float var = s2.w * inv - mean * mean;
        float rs = rsqrtf(var + 1e-5f);
        float t = ga.w * (m.w - mean); t = t * rs; t += be.w; o.w = fmaxf(t, 0.f);
    }
    *(float4*)&out[(size_t)q * DOUT + c] = o;
}

extern "C" void kernel_launch(void* const* d_in, const int* in_sizes, int n_in,
                              void* d_out, int out_size, void* d_ws, size_t ws_size,
                              hipStream_t stream) {
    (void)in_sizes; (void)n_in; (void)out_size; (void)d_ws; (void)ws_size;
    const float* feat  = (const float*)d_in[0];
    const float* xyz   = (const float*)d_in[1];
    const float* W     = (const float*)d_in[2];
    const float* bias  = (const float*)d_in[3];
    const float* gamma = (const float*)d_in[4];
    const float* beta  = (const float*)d_in[5];
    float* out = (float*)d_out;

    k_fused1<<<BB + 2048 + 32, 512, 0, stream>>>(feat, xyz, W, bias, out);
    k_knn   <<<BB * SS / 16, 1024, 0, stream>>>(xyz, out);
    k_stats <<<256, 256, 0, stream>>>();
    k_final <<<2048, 256, 0, stream>>>(gamma, beta, out);
}

// Round 5
// 1020.903 us; speedup vs baseline: 2.5622x; 1.4730x over previous
//
#include <hip/hip_runtime.h>
#include <hip/hip_bf16.h>

#define BB 8
#define NN 4096
#define DIN 128
#define DOUT 256
#define SS 1024
#define KK 16

// Workspace in device globals: immune to ws_size, graph-capture-safe.
__device__ float g_g[(size_t)BB * NN * DOUT];     // 32 MB: g = feat @ W^T + b
__device__ int   g_knn[BB * SS * KK];
__device__ int   g_wcount[BB * NN];
__device__ float g_S1[DOUT];
__device__ float g_S2[DOUT];

__device__ __forceinline__ unsigned long long umax64(unsigned long long a, unsigned long long b) {
    return a > b ? a : b;
}

// ---------------------------------------------------------------------------
// Kernel 1: blocks [0,8)   : FPS per batch (exact f64 min-update, 52-bit key
//                            argmax, DPP wave reduce, 1 barrier/iter)
//           blocks [8,2056): GEMM g = feat @ W^T + b  (M=32768,K=128,N=256)
//           blocks [2056,2088): zero wcount / S1 / S2
// ---------------------------------------------------------------------------
__global__ __launch_bounds__(512) void k_fused1(
    const float* __restrict__ feat, const float* __restrict__ xyz,
    const float* __restrict__ W, const float* __restrict__ bias,
    float* __restrict__ out)
{
    __shared__ __align__(16) float smem[16384]; // xyz as float4[4096] OR gemm tiles
    __shared__ __align__(16) unsigned long long swk64[2][8];

    if (blockIdx.x < BB) {
        #pragma clang fp contract(off)
        // FPS. dist64 updates are bit-identical to numpy float64:
        // dx = (f64)x - (f64)lx; m = dx*dx (unfused); d = (m1+m2)+m3; min.
        // Selection key: top-52 bits of f64 dist | (4095-idx): argmax with
        // first-occurrence tie-break (np.argmax semantics).
        const int b = blockIdx.x, tid = threadIdx.x;
        const float* bx = xyz + (size_t)b * NN * 3;
        for (int i = 0; i < 8; ++i) {
            int p = tid + i * 512;
            float4 v; v.x = bx[p*3]; v.y = bx[p*3+1]; v.z = bx[p*3+2]; v.w = 0.f;
            ((float4*)smem)[p] = v;
        }
        __syncthreads();
        float px[8], py[8], pz[8];
        double dist64[8];
        unsigned fb[8];
        unsigned long long key[8];
        const int gbase = tid * 8;
        const unsigned long long D0 =
            ((unsigned long long)__double_as_longlong(1e10)) & ~0xFFFULL;
        #pragma unroll
        for (int r = 0; r < 8; ++r) {
            float4 v = ((float4*)smem)[gbase + r];
            px[r] = v.x; py[r] = v.y; pz[r] = v.z;
            dist64[r] = 1e10;
            fb[r] = __float_as_uint(1e10f);      // 1e10 exact in f32
            key[r] = D0 | (unsigned long long)(4095 - (gbase + r));
        }
        float4 c0 = ((float4*)smem)[0];
        float lxf = c0.x, lyf = c0.y, lzf = c0.z;
        double lxd = (double)lxf, lyd = (double)lyf, lzd = (double)lzf;
        float* oxyz = out + (size_t)BB * SS * DOUT;
        if (tid == 0) {
            oxyz[(size_t)(b*SS)*3]   = lxf;
            oxyz[(size_t)(b*SS)*3+1] = lyf;
            oxyz[(size_t)(b*SS)*3+2] = lzf;
        }
        for (int s = 1; s < SS; ++s) {
            // --- distance min-update: f32 fast path, exact f64 slow path ---
            #pragma unroll
            for (int r = 0; r < 8; ++r) {
                float dx = px[r] - lxf, dy = py[r] - lyf, dz = pz[r] - lzf;
                float d32 = fmaf(dx, dx, fmaf(dy, dy, dz * dz));
                unsigned du = __float_as_uint(d32);
                // skip is safe: du >= fb+16 (16 ulps) => true d > dist64
                if (du < fb[r] + 16u) {
                    double ddx = (double)px[r] - lxd;
                    double ddy = (double)py[r] - lyd;
                    double ddz = (double)pz[r] - lzd;
                    double m1 = ddx*ddx, m2 = ddy*ddy, m3 = ddz*ddz;
                    double d = (m1 + m2) + m3;
                    if (d < dist64[r]) {
                        dist64[r] = d;
                        fb[r] = __float_as_uint((float)d);
                        key[r] = (((unsigned long long)__double_as_longlong(d)) & ~0xFFFULL)
                                 | (unsigned long long)(4095 - (gbase + r));
                    }
                }
            }
            // --- per-thread 8 -> 1 key max ---
            unsigned long long kk;
            {
                unsigned long long a0 = umax64(key[0], key[1]);
                unsigned long long a1 = umax64(key[2], key[3]);
                unsigned long long a2 = umax64(key[4], key[5]);
                unsigned long long a3 = umax64(key[6], key[7]);
                kk = umax64(umax64(a0, a1), umax64(a2, a3));
            }
            // --- wave64 max via DPP (VALU latency, no ds_swizzle) ---
#define DPP64(CTRL) { \
    int _lo = __builtin_amdgcn_update_dpp(0, (int)(unsigned)kk, CTRL, 0xf, 0xf, true); \
    int _hi = __builtin_amdgcn_update_dpp(0, (int)(unsigned)(kk >> 32), CTRL, 0xf, 0xf, true); \
    unsigned long long _o = (((unsigned long long)(unsigned)_hi) << 32) | (unsigned)_lo; \
    if (_o > kk) kk = _o; }
            DPP64(0x111)  // row_shr:1
            DPP64(0x112)  // row_shr:2
            DPP64(0x114)  // row_shr:4
            DPP64(0x118)  // row_shr:8
            DPP64(0x142)  // row_bcast:15
            DPP64(0x143)  // row_bcast:31
#undef DPP64
            // lane 63 of each wave holds the wave max
            if ((tid & 63) == 63) swk64[s & 1][tid >> 6] = kk;
            __syncthreads();
            const unsigned long long* sw = swk64[s & 1];
            unsigned long long k01 = umax64(sw[0], sw[1]);
            unsigned long long k23 = umax64(sw[2], sw[3]);
            unsigned long long k45 = umax64(sw[4], sw[5]);
            unsigned long long k67 = umax64(sw[6], sw[7]);
            unsigned long long kmax = umax64(umax64(k01, k23), umax64(k45, k67));
            int widx = 4095 - (int)(kmax & 0xFFFULL);
            float4 c = ((float4*)smem)[widx];
            lxf = c.x; lyf = c.y; lzf = c.z;
            lxd = (double)c.x; lyd = (double)c.y; lzd = (double)c.z;
            if (tid == 0) {
                oxyz[(size_t)(b*SS+s)*3]   = c.x;
                oxyz[(size_t)(b*SS+s)*3+1] = c.y;
                oxyz[(size_t)(b*SS+s)*3+2] = c.z;
            }
        }
    } else if (blockIdx.x < BB + 2048) {
        // GEMM: BM=64, BN=64, BK=32, 512 threads, 2x4 per thread (validated r2)
        int gi = blockIdx.x - BB;
        int mt = gi & 511, nt = gi >> 9;
        int rbase = mt * 64, cbase = nt * 64;
        float* As = smem;            // [64][36]
        float* Bs = smem + 64 * 36;  // [32][68]
        int tid = threadIdx.x;
        int tx = tid & 15, ty = tid >> 4;
        int c0 = tx * 4, r0 = ty * 2;
        int lr = tid >> 3;          // 0..63
        int lk = (tid & 7) * 4;     // 0..28
        float acc[2][4] = {{0.f,0.f,0.f,0.f},{0.f,0.f,0.f,0.f}};
        for (int kc = 0; kc < 4; ++kc) {
            __syncthreads();
            float4 av = *(const float4*)&feat[(size_t)(rbase + lr) * DIN + kc*32 + lk];
            *(float4*)&As[lr * 36 + lk] = av;
            float4 wv = *(const float4*)&W[(size_t)(cbase + lr) * DIN + kc*32 + lk];
            Bs[(lk+0)*68 + lr] = wv.x;
            Bs[(lk+1)*68 + lr] = wv.y;
            Bs[(lk+2)*68 + lr] = wv.z;
            Bs[(lk+3)*68 + lr] = wv.w;
            __syncthreads();
            const float* Ar0 = &As[r0 * 36];
            const float* Ar1 = Ar0 + 36;
            #pragma unroll
            for (int k = 0; k < 32; ++k) {
                float a0 = Ar0[k], a1 = Ar1[k];
                float4 bv = *(float4*)&Bs[k * 68 + c0];
                acc[0][0] += a0 * bv.x; acc[0][1] += a0 * bv.y;
                acc[0][2] += a0 * bv.z; acc[0][3] += a0 * bv.w;
                acc[1][0] += a1 * bv.x; acc[1][1] += a1 * bv.y;
                acc[1][2] += a1 * bv.z; acc[1][3] += a1 * bv.w;
            }
        }
        float4 bb4 = *(const float4*)&bias[cbase + c0];
        float4 o0, o1;
        o0.x = acc[0][0] + bb4.x; o0.y = acc[0][1] + bb4.y;
        o0.z = acc[0][2] + bb4.z; o0.w = acc[0][3] + bb4.w;
        o1.x = acc[1][0] + bb4.x; o1.y = acc[1][1] + bb4.y;
        o1.z = acc[1][2] + bb4.z; o1.w = acc[1][3] + bb4.w;
        *(float4*)&g_g[(size_t)(rbase + r0)     * DOUT + cbase + c0] = o0;
        *(float4*)&g_g[(size_t)(rbase + r0 + 1) * DOUT + cbase + c0] = o1;
    } else {
        int zi = blockIdx.x - (BB + 2048);
        int t = zi * 512 + threadIdx.x;     // 0..16383
        g_wcount[t] = 0;
        g_wcount[t + 16384] = 0;
        if (t < DOUT) { g_S1[t] = 0.f; g_S2[t] = 0.f; }
    }
}

// ---------------------------------------------------------------------------
// Kernel 2: KNN via per-wave histogram select + exact f64 resolve (r4-passing)
// ---------------------------------------------------------------------------
__global__ __launch_bounds__(1024) void k_knn(
    const float* __restrict__ xyz, const float* __restrict__ out)
{
    __shared__ __align__(16) float4 pts[NN];   // 64 KB
    __shared__ unsigned hist[16][512];         // 32 KB
    __shared__ int cand[16][128];              //  8 KB
    __shared__ int cnt[16];
    const int tid = threadIdx.x, lane = tid & 63, w = tid >> 6;
    const int q = blockIdx.x * 16 + w;         // 64 blocks per batch
    const int b = blockIdx.x >> 6;
    const float* bx = xyz + (size_t)b * NN * 3;
    for (int i = 0; i < 4; ++i) {
        int p = tid + i * 1024;
        float4 v; v.x = bx[p*3]; v.y = bx[p*3+1]; v.z = bx[p*3+2]; v.w = 0.f;
        pts[p] = v;
    }
    { unsigned* h = &hist[0][0];
      #pragma unroll
      for (int i = 0; i < 8; ++i) h[tid + i * 1024] = 0u; }
    if (tid < 16) cnt[tid] = 0;
    __syncthreads();

    const float* sx = out + (size_t)BB * SS * DOUT + (size_t)q * 3;
    const float qxf = sx[0], qyf = sx[1], qzf = sx[2];
    // pass 1: histogram f32 distance bits
    unsigned minub = 0xFFFFFFFFu;
    for (int t = 0; t < 64; ++t) {
        int n = t * 64 + lane;
        float4 p = pts[n];
        float dx = qxf - p.x, dy = qyf - p.y, dz = qzf - p.z;
        float df = fmaf(dz, dz, fmaf(dy, dy, dx * dx));
        unsigned ub = __float_as_uint(df);
        minub = ub < minub ? ub : minub;
        unsigned bk = ub < 0x30800000u ? 0u : ((ub - 0x30800000u) >> 19);
        bk = bk > 511u ? 511u : bk;
        atomicAdd(&hist[w][bk], 1u);
    }
    #pragma unroll
    for (int m = 1; m < 64; m <<= 1) {
        unsigned o = __shfl_xor(minub, m);
        minub = o < minub ? o : minub;
    }
    unsigned mb = minub < 0x30800000u ? 0u : ((minub - 0x30800000u) >> 19);
    mb = mb > 511u ? 511u : mb;
    // scan own histogram row for the bucket containing rank 16
    int Tb = 511;
    unsigned base = 0;
    for (int ch = (int)(mb >> 6); ch < 8; ++ch) {
        unsigned v = hist[w][ch * 64 + lane];
        #pragma unroll
        for (int m = 1; m < 64; m <<= 1) {
            unsigned t2 = __shfl_up(v, m);
            if (lane >= m) v += t2;
        }
        unsigned tot = __shfl(v, 63);
        unsigned long long msk = __ballot(base + v >= 16u);
        if (msk) { Tb = ch * 64 + (__ffsll(msk) - 1); break; }
        base += tot;
    }
    unsigned Tcap = (unsigned)Tb + 1u; Tcap = Tcap > 511u ? 511u : Tcap;
    // pass 2: collect candidates (identical df computation => identical bits)
    for (int t = 0; t < 64; ++t) {
        int n = t * 64 + lane;
        float4 p = pts[n];
        float dx = qxf - p.x, dy = qyf - p.y, dz = qzf - p.z;
        float df = fmaf(dz, dz, fmaf(dy, dy, dx * dx));
        unsigned ub = __float_as_uint(df);
        unsigned bk = ub < 0x30800000u ? 0u : ((ub - 0x30800000u) >> 19);
        bk = bk > 511u ? 511u : bk;
        if (bk <= Tcap) {
            int slot = atomicAdd(&cnt[w], 1);
            if (slot < 128) cand[w][slot] = n;
        }
    }
    {
        #pragma clang fp contract(off)
        // wave-local LDS produced by own lanes: no block barrier needed
        int count = cnt[w]; count = count > 128 ? 128 : count;
        const double qx = (double)qxf, qy = (double)qyf, qz = (double)qzf;
        int i0 = lane < count ? cand[w][lane] : -1;
        int i1 = (lane + 64) < count ? cand[w][lane + 64] : -1;
        double d0 = 1e300, d1 = 1e300;
        if (i0 >= 0) {
            float4 p = pts[i0];
            double dx = qx - (double)p.x, dy = qy - (double)p.y, dz = qz - (double)p.z;
            double m1 = dx*dx, m2 = dy*dy, m3 = dz*dz;
            d0 = (m1 + m2) + m3;
        }
        if (i1 >= 0) {
            float4 p = pts[i1];
            double dx = qx - (double)p.x, dy = qy - (double)p.y, dz = qz - (double)p.z;
            double m1 = dx*dx, m2 = dy*dy, m3 = dz*dz;
            d1 = (m1 + m2) + m3;
        }
        int r0 = 0, r1 = 0;
        for (int i = 0; i < count; ++i) {
            double od; int oi;
            if (i < 64) { od = __shfl(d0, i);      oi = __shfl(i0, i); }
            else        { od = __shfl(d1, i - 64); oi = __shfl(i1, i - 64); }
            if ((od < d0) || (od == d0 && oi < i0)) ++r0;
            if ((od < d1) || (od == d1 && oi < i1)) ++r1;
        }
        if (i0 >= 0 && r0 < KK) {
            g_knn[(size_t)q * KK + r0] = i0;
            atomicAdd(&g_wcount[b * NN + i0], 1);
        }
        if (i1 >= 0 && r1 < KK) {
            g_knn[(size_t)q * KK + r1] = i1;
            atomicAdd(&g_wcount[b * NN + i1], 1);
        }
    }
}

// ---------------------------------------------------------------------------
// Kernel 3: weighted per-channel sums for BN stats
// ---------------------------------------------------------------------------
__global__ __launch_bounds__(256) void k_stats()
{
    int tid = threadIdx.x;
    int rbase = blockIdx.x * 128;
    float a1 = 0.f, a2 = 0.f;
    for (int i = 0; i < 128; ++i) {
        int row = rbase + i;
        int w = g_wcount[row];
        if (w) {
            float v = g_g[(size_t)row * DOUT + tid];
            float wf = (float)w;
            a1 += wf * v;
            a2 += wf * v * v;
        }
    }
    atomicAdd(&g_S1[tid], a1);
    atomicAdd(&g_S2[tid], a2);
}

// ---------------------------------------------------------------------------
// Kernel 4: per-query max over K, then BN affine + ReLU (commutes: scale>0)
// ---------------------------------------------------------------------------
__global__ __launch_bounds__(256) void k_final(
    const float* __restrict__ gamma, const float* __restrict__ beta,
    float* __restrict__ out)
{
    int w = threadIdx.x >> 6, lane = threadIdx.x & 63;
    int q = blockIdx.x * 4 + w;       // 0..8191
    int b = q >> 10;
    int c = lane * 4;
    const int* ki = g_knn + (size_t)q * KK;
    float4 m; m.x = m.y = m.z = m.w = -1e30f;
    for (int k = 0; k < KK; ++k) {
        int idx = ki[k];
        float4 v = *(const float4*)&g_g[((size_t)(b * NN + idx)) * DOUT + c];
        m.x = fmaxf(m.x, v.x); m.y = fmaxf(m.y, v.y);
        m.z = fmaxf(m.z, v.z); m.w = fmaxf(m.w, v.w);
    }
    const float inv = 1.0f / 131072.0f;
    float4 s1 = *(const float4*)&g_S1[c];
    float4 s2 = *(const float4*)&g_S2[c];
    float4 ga = *(const float4*)&gamma[c];
    float4 be = *(const float4*)&beta[c];
    float4 o;
    {
        float mean = s1.x * inv; float var = s2.x * inv - mean * mean;
        float rs = rsqrtf(var + 1e-5f);
        float t = ga.x * (m.x - mean); t = t * rs; t += be.x; o.x = fmaxf(t, 0.f);
    }
    {
        float mean = s1.y * inv; float var = s2.y * inv - mean * mean;
        float rs = rsqrtf(var + 1e-5f);
        float t = ga.y * (m.y - mean); t = t * rs; t += be.y; o.y = fmaxf(t, 0.f);
    }
    {
        float mean = s1.z * inv; float var = s2.z * inv - mean * mean;
        float rs = rsqrtf(var + 1e-5f);
        float t = ga.z * (m.z - mean); t = t * rs; t += be.z; o.z = fmaxf(t, 0.f);
    }
    {
        float mean = s1.w * inv; float var = s2.w * inv - mean * mean;
        float rs = rsqrtf(var + 1e-5f);
        float t = ga.w * (m.w - mean); t = t * rs; t += be.w; o.w = fmaxf(t, 0.f);
    }
    *(float4*)&out[(size_t)q * DOUT + c] = o;
}

extern "C" void kernel_launch(void* const* d_in, const int* in_sizes, int n_in,
                              void* d_out, int out_size, void* d_ws, size_t ws_size,
                              hipStream_t stream) {
    (void)in_sizes; (void)n_in; (void)out_size; (void)d_ws; (void)ws_size;
    const float* feat  = (const float*)d_in[0];
    const float* xyz   = (const float*)d_in[1];
    const float* W     = (const float*)d_in[2];
    const float* bias  = (const float*)d_in[3];
    const float* gamma = (const float*)d_in[4];
    const float* beta  = (const float*)d_in[5];
    float* out = (float*)d_out;

    k_fused1<<<BB + 2048 + 32, 512, 0, stream>>>(feat, xyz, W, bias, out);
    k_knn   <<<BB * SS / 16, 1024, 0, stream>>>(xyz, out);
    k_stats <<<256, 256, 0, stream>>>();
    k_final <<<2048, 256, 0, stream>>>(gamma, beta, out);
}